// Round 1
// baseline (561.133 us; speedup 1.0000x reference)
//
#include <hip/hip_runtime.h>
#include <math.h>

// Problem constants
#define BB 8
#define NN 512
#define DD 256
#define BN (BB*NN)   // 4096

// Workspace layout (float offsets). Total ~11.2M floats = 44.7 MB.
#define OFF_S0   0u         // symbols0            [4096][256]
#define OFF_ASUM 1048576u   // per-batch sums      [8][256]
#define OFF_S    1050624u   // S rows              [4096][1536]  (S_0..S_4, Stot)
#define OFF_CNT  7342080u   // counts (float)      [4096][8]     (r=0..4 used)
#define OFF_WCAT 7374848u   // Wcat                [1536][256]   (W_r - W_5 ; W_5)
#define OFF_RB   7768064u   // rbcat               [6][256]      (b_r - b_5 ; 511*b_5)
#define OFF_WBIG 7769600u   // Wbig                [256][1024]   (h1W0|h1W1|h1W2|outW)
#define OFF_BBIG 8031744u   // bbig                [1024]        (h1b0|h1b1|h1b2|outb)
#define OFF_H    8032768u   // gelu activations    [4096][768]

// d_out layout (floats)
#define OUT0_OFF   0u        // output  [8][512][256]
#define INTERP_OFF 1048576u  // interp  [3][4096]  (exoteric, esoteric, sacred)
#define SYM_OFF    1060864u  // symbols [8][512][256]

__device__ __forceinline__ float gelu_exact(float x) {
    return 0.5f * x * (1.0f + erff(x * 0.70710678118654752f));
}

// ---------------------------------------------------------------- prep ----
__global__ __launch_bounds__(256) void prep_kernel(
    const float* __restrict__ relW, const float* __restrict__ relb,
    const float* __restrict__ h1W,  const float* __restrict__ h1b,
    const float* __restrict__ outW, const float* __restrict__ outb,
    float* __restrict__ ws)
{
    int idx = blockIdx.x * 256 + threadIdx.x;   // grid covers 393216
    // Wcat [1536][256]: rows r*256+d ; r<5 -> W_r - W_5 ; r==5 -> W_5
    {
        int row = idx >> 8, col = idx & 255;
        int r = row >> 8, d = row & 255;
        float w5 = relW[(5 * DD + d) * DD + col];
        ws[OFF_WCAT + idx] = (r < 5) ? (relW[(r * DD + d) * DD + col] - w5) : w5;
    }
    // Wbig [256][1024]
    if (idx < 262144) {
        int d = idx >> 10, c = idx & 1023;
        float v;
        if (c < 768) { int r = c >> 8, e = c & 255; v = h1W[(r * DD + d) * DD + e]; }
        else         { v = outW[d * DD + (c - 768)]; }
        ws[OFF_WBIG + idx] = v;
    }
    // rbcat [6][256]
    if (idx < 1536) {
        int r = idx >> 8, col = idx & 255;
        float b5 = relb[5 * DD + col];
        ws[OFF_RB + idx] = (r < 5) ? (relb[r * DD + col] - b5) : (float)(NN - 1) * b5;
    }
    // bbig [1024]
    if (idx < 1024) {
        ws[OFF_BBIG + idx] = (idx < 768) ? h1b[idx] : outb[idx - 768];
    }
}

// -------------------------------------------------------------- gather ----
__global__ __launch_bounds__(256) void gather_kernel(
    const int* __restrict__ ids, const float* __restrict__ symt,
    const float* __restrict__ layt, float* __restrict__ s0)
{
    int idx = blockIdx.x * 256 + threadIdx.x;   // 1048576 total
    int row = idx >> 8, c = idx & 255;
    int id = ids[row];
    s0[idx] = symt[id * DD + c] + layt[id * DD + c];
}

// ------------------------------------------------------------ batchsum ----
__global__ __launch_bounds__(256) void batchsum_kernel(
    const float* __restrict__ s0, float* __restrict__ Asum)
{
    int b = blockIdx.x, e = threadIdx.x;
    float s = 0.f;
    for (int n = 0; n < NN; n++) s += s0[((size_t)b * NN + n) * DD + e];
    Asum[b * DD + e] = s;
}

// --------------------------------------------------------- grammar agg ----
// Block = (b, tile of 8 j's). Threads = d (256). Computes S_0..S_4, Stot
// per j plus relation counts. Relation codes are wave-uniform -> scalarized
// via readfirstlane; uniform switch avoids both divergence and 5x predicated FMAs.
__global__ __launch_bounds__(256) void grammar_agg(
    const float* __restrict__ positions, const float* __restrict__ s0,
    const float* __restrict__ Asum, float* __restrict__ Sws, float* __restrict__ cntws)
{
    int blk = blockIdx.x;            // 512 = 8 b * 64 jtiles
    int b = blk >> 6;
    int j0 = (blk & 63) << 3;
    int tid = threadIdx.x;           // = d
    __shared__ float px[NN], py[NN];
    __shared__ unsigned int relp[NN];
    __shared__ int cnts[8 * 5];

    for (int i = tid; i < NN; i += 256) {
        float2 p = ((const float2*)positions)[b * NN + i];
        px[i] = p.x; py[i] = p.y;
    }
    if (tid < 40) cnts[tid] = 0;
    __syncthreads();

    float xj[8], yj[8];
#pragma unroll
    for (int t = 0; t < 8; t++) { xj[t] = px[j0 + t]; yj[t] = py[j0 + t]; }

    // classify: rel[b,i,j], self forced to class 5 (handled by Stot path)
    for (int i = tid; i < NN; i += 256) {
        float xi = px[i], yi = py[i];
        unsigned int pk = 0;
#pragma unroll
        for (int t = 0; t < 8; t++) {
            float dx = xj[t] - xi, dy = yj[t] - yi;
            int r;
            if      (dy >  0.5f) r = 0;
            else if (dy < -0.5f) r = 1;
            else if (dx < -0.5f) r = 2;
            else if (dx >  0.5f) r = 3;
            else if (fabsf(dx) < 0.3f && fabsf(dy) < 0.3f) r = 4;
            else r = 5;
            if (i == j0 + t) r = 5;          // exclude self
            if (r < 5) atomicAdd(&cnts[t * 5 + r], 1);
            pk |= (unsigned)r << (3 * t);
        }
        relp[i] = pk;
    }
    __syncthreads();

    float acc[5][8];
#pragma unroll
    for (int r = 0; r < 5; r++)
#pragma unroll
        for (int t = 0; t < 8; t++) acc[r][t] = 0.f;

    const float* srow = s0 + (size_t)b * NN * DD + tid;
    for (int i = 0; i < NN; i++) {
        float s = srow[(size_t)i * DD];
        unsigned int pk = (unsigned)__builtin_amdgcn_readfirstlane((int)relp[i]);
#pragma unroll
        for (int t = 0; t < 8; t++) {
            unsigned int r = (pk >> (3 * t)) & 7u;
            switch (r) {
                case 0: acc[0][t] += s; break;
                case 1: acc[1][t] += s; break;
                case 2: acc[2][t] += s; break;
                case 3: acc[3][t] += s; break;
                case 4: acc[4][t] += s; break;
                default: break;
            }
        }
    }

    float a_d = Asum[b * DD + tid];
#pragma unroll
    for (int t = 0; t < 8; t++) {
        int j = j0 + t;
        size_t base = (size_t)(b * NN + j) * (6 * DD);
#pragma unroll
        for (int r = 0; r < 5; r++) Sws[base + r * DD + tid] = acc[r][t];
        Sws[base + 5 * DD + tid] = a_d - s0[((size_t)b * NN + j) * DD + tid];
    }
    if (tid < 40) {
        int t = tid / 5, r = tid % 5;
        cntws[(size_t)(b * NN + j0 + t) * 8 + r] = (float)cnts[t * 5 + r];
    }
}

// ----------------------------------------------------------------- gemm1 --
// symbols_final[4096][256] = Sws[4096][1536] @ Wcat[1536][256] + s0 + bias
__global__ __launch_bounds__(256) void gemm1_kernel(
    const float* __restrict__ Aw, const float* __restrict__ Wc,
    const float* __restrict__ s0, const float* __restrict__ cnt,
    const float* __restrict__ rbcat, float* __restrict__ symout)
{
    const int K = 1536;
    __shared__ float As[16][68];
    __shared__ float Ws[16][68];
    int tid = threadIdx.x;
    int tx = tid & 15, ty = tid >> 4;
    int row0 = blockIdx.y * 64, col0 = blockIdx.x * 64;
    int lr = tid >> 2, lk = tid & 3;
    int lwk = tid >> 4, lwc = tid & 15;
    float acc[4][4] = {};

    for (int k0 = 0; k0 < K; k0 += 16) {
        float4 a = *(const float4*)&Aw[(size_t)(row0 + lr) * K + k0 + lk * 4];
        float4 w = *(const float4*)&Wc[(size_t)(k0 + lwk) * DD + col0 + lwc * 4];
        __syncthreads();
        As[lk * 4 + 0][lr] = a.x; As[lk * 4 + 1][lr] = a.y;
        As[lk * 4 + 2][lr] = a.z; As[lk * 4 + 3][lr] = a.w;
        *(float4*)&Ws[lwk][lwc * 4] = w;
        __syncthreads();
#pragma unroll
        for (int kk = 0; kk < 16; kk++) {
            float av[4], wv[4];
            *(float4*)av = *(const float4*)&As[kk][ty * 4];
            *(float4*)wv = *(const float4*)&Ws[kk][tx * 4];
#pragma unroll
            for (int i2 = 0; i2 < 4; i2++)
#pragma unroll
                for (int j2 = 0; j2 < 4; j2++) acc[i2][j2] += av[i2] * wv[j2];
        }
    }
    // epilogue: + symbols0 + count-weighted relation bias
    int colb = col0 + tx * 4;
    float rbv[6][4];
#pragma unroll
    for (int r = 0; r < 6; r++)
#pragma unroll
        for (int j2 = 0; j2 < 4; j2++) rbv[r][j2] = rbcat[r * DD + colb + j2];
#pragma unroll
    for (int i2 = 0; i2 < 4; i2++) {
        int row = row0 + ty * 4 + i2;
        float c5[5];
#pragma unroll
        for (int r = 0; r < 5; r++) c5[r] = cnt[(size_t)row * 8 + r];
#pragma unroll
        for (int j2 = 0; j2 < 4; j2++) {
            float v = acc[i2][j2] + s0[(size_t)row * DD + colb + j2] + rbv[5][j2];
#pragma unroll
            for (int r = 0; r < 5; r++) v += c5[r] * rbv[r][j2];
            symout[(size_t)row * DD + colb + j2] = v;
        }
    }
}

// ----------------------------------------------------------------- gemm2 --
// [4096][256] @ Wbig[256][1024]; cols<768 -> gelu -> Hws; cols>=768 -> out0
__global__ __launch_bounds__(256) void gemm2_kernel(
    const float* __restrict__ Aw, const float* __restrict__ Wb,
    const float* __restrict__ bbig, float* __restrict__ Hws, float* __restrict__ out0)
{
    const int K = 256, NC = 1024;
    __shared__ float As[16][68];
    __shared__ float Ws[16][68];
    int tid = threadIdx.x;
    int tx = tid & 15, ty = tid >> 4;
    int row0 = blockIdx.y * 64, col0 = blockIdx.x * 64;
    int lr = tid >> 2, lk = tid & 3;
    int lwk = tid >> 4, lwc = tid & 15;
    float acc[4][4] = {};

    for (int k0 = 0; k0 < K; k0 += 16) {
        float4 a = *(const float4*)&Aw[(size_t)(row0 + lr) * K + k0 + lk * 4];
        float4 w = *(const float4*)&Wb[(size_t)(k0 + lwk) * NC + col0 + lwc * 4];
        __syncthreads();
        As[lk * 4 + 0][lr] = a.x; As[lk * 4 + 1][lr] = a.y;
        As[lk * 4 + 2][lr] = a.z; As[lk * 4 + 3][lr] = a.w;
        *(float4*)&Ws[lwk][lwc * 4] = w;
        __syncthreads();
#pragma unroll
        for (int kk = 0; kk < 16; kk++) {
            float av[4], wv[4];
            *(float4*)av = *(const float4*)&As[kk][ty * 4];
            *(float4*)wv = *(const float4*)&Ws[kk][tx * 4];
#pragma unroll
            for (int i2 = 0; i2 < 4; i2++)
#pragma unroll
                for (int j2 = 0; j2 < 4; j2++) acc[i2][j2] += av[i2] * wv[j2];
        }
    }
    int colb = col0 + tx * 4;
#pragma unroll
    for (int i2 = 0; i2 < 4; i2++) {
        int row = row0 + ty * 4 + i2;
#pragma unroll
        for (int j2 = 0; j2 < 4; j2++) {
            int c = colb + j2;
            float v = acc[i2][j2] + bbig[c];
            if (col0 < 768) Hws[(size_t)row * 768 + c] = gelu_exact(v);
            else            out0[(size_t)row * DD + (c - 768)] = v;
        }
    }
}

// ---------------------------------------------------------------- interp --
// interp[r][bn] = sum_e Hws[bn][r*256+e] * h2W[r][e] + h2b[r]
__global__ __launch_bounds__(256) void interp_kernel(
    const float* __restrict__ Hws, const float* __restrict__ h2W,
    const float* __restrict__ h2b, float* __restrict__ outI)
{
    int wave = threadIdx.x >> 6, lane = threadIdx.x & 63;
    int bn = blockIdx.x * 4 + wave;
#pragma unroll
    for (int r = 0; r < 3; r++) {
        float s = 0.f;
#pragma unroll
        for (int q = 0; q < 4; q++) {
            int e = lane + 64 * q;
            s += Hws[(size_t)bn * 768 + r * 256 + e] * h2W[r * 256 + e];
        }
        for (int off = 32; off > 0; off >>= 1) s += __shfl_down(s, off);
        if (lane == 0) outI[r * BN + bn] = s + h2b[r];
    }
}

// ---------------------------------------------------------------- launch --
extern "C" void kernel_launch(void* const* d_in, const int* in_sizes, int n_in,
                              void* d_out, int out_size, void* d_ws, size_t ws_size,
                              hipStream_t stream)
{
    const int*   ids  = (const int*)d_in[0];
    const float* pos  = (const float*)d_in[1];
    const float* symt = (const float*)d_in[2];
    const float* layt = (const float*)d_in[3];
    const float* relW = (const float*)d_in[4];
    const float* relb = (const float*)d_in[5];
    const float* h1W  = (const float*)d_in[6];
    const float* h1b  = (const float*)d_in[7];
    const float* h2W  = (const float*)d_in[8];
    const float* h2b  = (const float*)d_in[9];
    const float* outW = (const float*)d_in[10];
    const float* outb = (const float*)d_in[11];
    float* out = (float*)d_out;
    float* ws  = (float*)d_ws;

    prep_kernel<<<1536, 256, 0, stream>>>(relW, relb, h1W, h1b, outW, outb, ws);
    gather_kernel<<<4096, 256, 0, stream>>>(ids, symt, layt, ws + OFF_S0);
    batchsum_kernel<<<BB, 256, 0, stream>>>(ws + OFF_S0, ws + OFF_ASUM);
    grammar_agg<<<512, 256, 0, stream>>>(pos, ws + OFF_S0, ws + OFF_ASUM,
                                         ws + OFF_S, ws + OFF_CNT);
    gemm1_kernel<<<dim3(4, 64), 256, 0, stream>>>(ws + OFF_S, ws + OFF_WCAT,
                                                  ws + OFF_S0, ws + OFF_CNT,
                                                  ws + OFF_RB, out + SYM_OFF);
    gemm2_kernel<<<dim3(16, 64), 256, 0, stream>>>(out + SYM_OFF, ws + OFF_WBIG,
                                                   ws + OFF_BBIG, ws + OFF_H, out + OUT0_OFF);
    interp_kernel<<<1024, 256, 0, stream>>>(ws + OFF_H, h2W, h2b, out + INTERP_OFF);
}